// Round 15
// baseline (156.556 us; speedup 1.0000x reference)
//
#include <hip/hip_runtime.h>

// MHA forward, full-bf16 MFMA pipeline.
// ws layout (bytes): xb[8MB] | Wt[6MB: [3][1024][1024] bf16 N-major] | Wot[2MB]
//                    | qkv[24MB: Q,K:[B][H][T][64], V:[B][H][64][T]] | Y[8MB]

typedef short v8s __attribute__((ext_vector_type(8)));
typedef float v4f __attribute__((ext_vector_type(4)));
typedef float v16f __attribute__((ext_vector_type(16)));

#define DEVI __device__ __forceinline__

#define B_SZ 2
#define T_SEQ 2048
#define NH 16
#define HS 64
#define CEMB 1024
#define MROWS (B_SZ * T_SEQ)   // 4096
#define KSZ 1024
// Q scale: 1/sqrt(64) * log2(e)  (attention softmax runs in exp2 domain)
#define SCALE_Q 0.18033688011112042f

DEVI unsigned short f2bf(float f) {
  union { float f; unsigned u; } c; c.f = f;
  unsigned u = c.u;
  unsigned r = (u + 0x7FFFu + ((u >> 16) & 1u)) >> 16;   // RNE
  return (unsigned short)r;
}

DEVI float exp2_fast(float x) {         // v_exp_f32 = 2^x
  float r;
  asm("v_exp_f32 %0, %1" : "=v"(r) : "v"(x));
  return r;
}

DEVI unsigned cvt_pk_bf16(float lo, float hi) {  // packs 2 f32 -> 2 bf16 (RNE)
  unsigned r;
  asm("v_cvt_pk_bf16_f32 %0, %1, %2" : "=v"(r) : "v"(lo), "v"(hi));
  return r;
}

// async global -> LDS, 16B per lane (wave-uniform LDS base + lane*16)
DEVI void gload_lds16(const void* g, void* l) {
  __builtin_amdgcn_global_load_lds(
      (const __attribute__((address_space(1))) void*)g,
      (__attribute__((address_space(3))) void*)l, 16, 0, 0);
}

// bijective XCD-contiguous block swizzle (requires nwg % 8 == 0)
DEVI int xcd_swz(int bid, int nwg) {
  int q = nwg >> 3;
  return (bid & 7) * q + (bid >> 3);
}

// ---------------- fused prep: x->bf16 + weight transposes (1 launch) -------
__global__ __launch_bounds__(256, 4) void prep_kernel(
    const float* __restrict__ x, const float* __restrict__ Wq,
    const float* __restrict__ Wk, const float* __restrict__ Wv,
    const float* __restrict__ Wo, unsigned short* __restrict__ xb,
    unsigned short* __restrict__ Wt, unsigned short* __restrict__ Wot) {
  int bid = blockIdx.x;
  if (bid < 2048) {
    int i = bid * 2048 + threadIdx.x * 8;
    float4 a = *(const float4*)(x + i);
    float4 b = *(const float4*)(x + i + 4);
    ushort4 o0, o1;
    o0.x = f2bf(a.x); o0.y = f2bf(a.y); o0.z = f2bf(a.z); o0.w = f2bf(a.w);
    o1.x = f2bf(b.x); o1.y = f2bf(b.y); o1.z = f2bf(b.z); o1.w = f2bf(b.w);
    *(ushort4*)(xb + i) = o0;
    *(ushort4*)(xb + i + 4) = o1;
    return;
  }
  __shared__ float tile[32][33];
  const float* in; unsigned short* out;
  int C, bx, by;
  if (bid < 5120) {
    int b2 = bid - 2048;
    int widx = b2 >> 10, rem = b2 & 1023;
    in = (widx == 0 ? Wq : (widx == 1 ? Wk : Wv));
    int z = rem >> 6;                     // head 0..15
    bx = rem & 1; by = (rem >> 1) & 31;
    C = 64;
    in += (size_t)z * 1024 * 64;
    out = Wt + ((size_t)widx << 20) + (size_t)z * 1024 * 64;
  } else {
    int rem = bid - 5120;
    C = 1024;
    bx = rem & 31; by = rem >> 5;
    in = Wo; out = Wot;
  }
  int c0 = bx * 32, r0 = by * 32;
  int tx = threadIdx.x & 31, ty = threadIdx.x >> 5;
#pragma unroll
  for (int j = 0; j < 4; ++j)
    tile[ty + j * 8][tx] = in[(size_t)(r0 + ty + j * 8) * C + c0 + tx];
  __syncthreads();
#pragma unroll
  for (int j = 0; j < 4; ++j)
    out[(size_t)(c0 + ty + j * 8) * 1024 + r0 + tx] = f2bf(tile[tx][ty + j * 8]);
}

// ------------- QKV GEMM: 128x128, 3-deep counted-vmcnt, V-transpose epi ----
__global__ __launch_bounds__(256, 3) void gemm_qkv(
    const unsigned short* __restrict__ A, const unsigned short* __restrict__ Bt,
    unsigned short* __restrict__ Cout, int nbx) {
  __shared__ __align__(16) unsigned char lds[49152];     // As[3]|Bs[3] / Vt_l
  unsigned short* As = (unsigned short*)lds;             // [3][4096]
  unsigned short* Bs = (unsigned short*)(lds + 24576);   // [3][4096]

  const int tid = threadIdx.x;
  const int lane = tid & 63, w = tid >> 6;
  const int wm = w >> 1, wn = w & 1;
  const int lr = lane & 15, lg = lane >> 4;

  const int wg = xcd_swz(blockIdx.x, gridDim.x);
  const int mb = (wg / nbx) * 128, nb = (wg % nbx) * 128;

  v4f acc[4][4];
  v4f zero = {0.f, 0.f, 0.f, 0.f};
#pragma unroll
  for (int i = 0; i < 4; ++i)
#pragma unroll
    for (int j = 0; j < 4; ++j) acc[i][j] = zero;

  const int srow = lane >> 2;
  const int sgcol = ((lane & 3) ^ (srow & 3)) * 8;
  const unsigned short* gA = A + (size_t)(mb + w * 32 + srow) * KSZ + sgcol;
  const unsigned short* gB = Bt + (size_t)(nb + w * 32 + srow) * KSZ + sgcol;
  unsigned short* lA = As + w * 1024;
  unsigned short* lB = Bs + w * 1024;

#define STAGE_G(buf, kb)                                        \
  do {                                                          \
    gload_lds16(gA + (kb), lA + (buf) * 4096);                  \
    gload_lds16(gA + (kb) + 16 * KSZ, lA + (buf) * 4096 + 512); \
    gload_lds16(gB + (kb), lB + (buf) * 4096);                  \
    gload_lds16(gB + (kb) + 16 * KSZ, lB + (buf) * 4096 + 512); \
  } while (0)

  STAGE_G(0, 0);
  STAGE_G(1, 32);
  STAGE_G(2, 64);

  const int NT = KSZ / 32;
  for (int t = 0; t < NT; ++t) {
    if (t < NT - 2)
      asm volatile("s_waitcnt vmcnt(8)" ::: "memory");
    else if (t == NT - 2)
      asm volatile("s_waitcnt vmcnt(4)" ::: "memory");
    else
      asm volatile("s_waitcnt vmcnt(0)" ::: "memory");
    __builtin_amdgcn_s_barrier();

    const int buf = t % 3;
    v8s af[4], bfr[4];
#pragma unroll
    for (int i = 0; i < 4; ++i) {
      int ra = wm * 64 + i * 16 + lr, rb = wn * 64 + i * 16 + lr;
      af[i]  = *(const v8s*)&As[buf * 4096 + ra * 32 + ((lg ^ (lr & 3)) << 3)];
      bfr[i] = *(const v8s*)&Bs[buf * 4096 + rb * 32 + ((lg ^ (lr & 3)) << 3)];
    }
#pragma unroll
    for (int i = 0; i < 4; ++i)
#pragma unroll
      for (int j = 0; j < 4; ++j)
        acc[i][j] = __builtin_amdgcn_mfma_f32_16x16x32_bf16(af[i], bfr[j], acc[i][j], 0, 0, 0);

    asm volatile("s_waitcnt lgkmcnt(0)" ::: "memory");
    __builtin_amdgcn_s_barrier();
    if (t + 3 < NT) STAGE_G(buf, (t + 3) * 32);
  }
#undef STAGE_G

  if ((wg % nbx) >= 16) {
    // ---- V-block epilogue: LDS transpose then t-contiguous 16B stores ----
    unsigned short* out = (unsigned short*)Cout;
#pragma unroll
    for (int i = 0; i < 4; ++i) {
      int tl0 = wm * 64 + i * 16 + lg * 4;
      int tc = tl0 >> 3, off = (tl0 & 7) * 2;
#pragma unroll
      for (int j = 0; j < 4; ++j) {
        int dl = wn * 64 + j * 16 + lr;
        unsigned lo = cvt_pk_bf16(acc[i][j][0], acc[i][j][1]);
        unsigned hi = cvt_pk_bf16(acc[i][j][2], acc[i][j][3]);
        unsigned char* p = lds + dl * 256 + ((tc ^ (dl & 15)) << 4) + off;
        *(unsigned*)p = lo;
        *(unsigned*)(p + 4) = hi;
      }
    }
    __syncthreads();
    int b = mb >> 11, mt = mb & 2047;
    int nrem0 = nb & 1023;
    unsigned short* Vg = out + (size_t)(2 * B_SZ * NH) * T_SEQ * HS;
#pragma unroll
    for (int it = 0; it < 8; ++it) {
      int dl = it * 16 + (tid >> 4);
      int tc = tid & 15;
      const unsigned char* p = lds + dl * 256 + ((tc ^ (dl & 15)) << 4);
      int4 vv = *(const int4*)p;
      int nrem = nrem0 + dl;
      int h = nrem >> 6, dd = nrem & 63;
      *(int4*)(Vg + ((size_t)(b * NH + h) * HS + dd) * T_SEQ + mt + tc * 8) = vv;
    }
    return;
  }

#pragma unroll
  for (int i = 0; i < 4; ++i) {
    int mrow0 = mb + wm * 64 + i * 16 + lg * 4;
#pragma unroll
    for (int j = 0; j < 4; ++j) {
      int ncol = nb + wn * 64 + j * 16 + lr;
      int p = ncol >> 10, rem = ncol & 1023, h = rem >> 6, d = rem & 63;
      float sc = (p == 0) ? SCALE_Q : 1.0f;
      unsigned short* out = (unsigned short*)Cout;
#pragma unroll
      for (int r = 0; r < 4; ++r) {
        int mrow = mrow0 + r;
        int b = mrow >> 11, t = mrow & 2047;
        out[((size_t)((p * B_SZ + b) * NH + h) * T_SEQ + t) * HS + d] =
            f2bf(acc[i][j][r] * sc);
      }
    }
  }
}

// ------------- out-proj GEMM: BM=64 x BN=128, 3-deep counted-vmcnt ---------
__global__ __launch_bounds__(256, 4) void gemm_proj(
    const unsigned short* __restrict__ A, const unsigned short* __restrict__ Bt,
    float* __restrict__ Cout, const float* __restrict__ bias, int nbx) {
  __shared__ __align__(16) unsigned short As[3][64 * 32];    // 4KB x3
  __shared__ __align__(16) unsigned short Bs[3][128 * 32];   // 8KB x3

  const int tid = threadIdx.x;
  const int lane = tid & 63, w = tid >> 6;
  const int wm = w >> 1, wn = w & 1;
  const int lr = lane & 15, lg = lane >> 4;

  const int wg = xcd_swz(blockIdx.x, gridDim.x);
  const int mb = (wg / nbx) * 64, nb = (wg % nbx) * 128;

  v4f acc[2][4];
  v4f zero = {0.f, 0.f, 0.f, 0.f};
#pragma unroll
  for (int i = 0; i < 2; ++i)
#pragma unroll
    for (int j = 0; j < 4; ++j) acc[i][j] = zero;

  const int srow = lane >> 2;
  const int sgcol = ((lane & 3) ^ (srow & 3)) * 8;
  const unsigned short* gA = A + (size_t)(mb + w * 16 + srow) * KSZ + sgcol;
  const unsigned short* gB = Bt + (size_t)(nb + w * 32 + srow) * KSZ + sgcol;
  unsigned short* lA = &As[0][0] + w * 512;
  unsigned short* lB = &Bs[0][0] + w * 1024;

#define STAGE_P(buf, kb)                                        \
  do {                                                          \
    gload_lds16(gA + (kb), lA + (buf) * 2048);                  \
    gload_lds16(gB + (kb), lB + (buf) * 4096);                  \
    gload_lds16(gB + (kb) + 16 * KSZ, lB + (buf) * 4096 + 512); \
  } while (0)

  STAGE_P(0, 0);
  STAGE_P(1, 32);
  STAGE_P(2, 64);

  const int NT = KSZ / 32;
  for (int t = 0; t < NT; ++t) {
    if (t < NT - 2)
      asm volatile("s_waitcnt vmcnt(6)" ::: "memory");
    else if (t == NT - 2)
      asm volatile("s_waitcnt vmcnt(3)" ::: "memory");
    else
      asm volatile("s_waitcnt vmcnt(0)" ::: "memory");
    __builtin_amdgcn_s_barrier();

    const int buf = t % 3;
    v8s af[2], bfr[4];
#pragma unroll
    for (int i = 0; i < 2; ++i) {
      int ra = wm * 32 + i * 16 + lr;
      af[i] = *(const v8s*)&As[buf][ra * 32 + ((lg ^ (lr & 3)) << 3)];
    }
#pragma unroll
    for (int j = 0; j < 4; ++j) {
      int rb = wn * 64 + j * 16 + lr;
      bfr[j] = *(const v8s*)&Bs[buf][rb * 32 + ((lg ^ (lr & 3)) << 3)];
    }
#pragma unroll
    for (int i = 0; i < 2; ++i)
#pragma unroll
      for (int j = 0; j < 4; ++j)
        acc[i][j] = __builtin_amdgcn_mfma_f32_16x16x32_bf16(af[i], bfr[j], acc[i][j], 0, 0, 0);

    asm volatile("s_waitcnt lgkmcnt(0)" ::: "memory");
    __builtin_amdgcn_s_barrier();
    if (t + 3 < NT) STAGE_P(buf, (t + 3) * 32);
  }
#undef STAGE_P

#pragma unroll
  for (int i = 0; i < 2; ++i) {
    int mrow0 = mb + wm * 32 + i * 16 + lg * 4;
#pragma unroll
    for (int j = 0; j < 4; ++j) {
      int ncol = nb + wn * 64 + j * 16 + lr;
      float bv = bias[ncol];
#pragma unroll
      for (int r = 0; r < 4; ++r)
        Cout[(size_t)(mrow0 + r) * CEMB + ncol] = acc[i][j][r] + bv;
    }
  }
}

// ------------- causal flash attention: 32x32 MFMA, sequential per-cf ------
// 256 thr = 4 waves; wave w owns q rows qc*128 + w*32..+31; KVBLK=128.
// All mappings (C-layout, causal mask, permlane B-frag) are r13-proven
// (absmax passed); restructured so only ONE v16f S is live at a time:
// per 32-kv block cf: QK^T -> mask -> per-cf online softmax (defer-max)
// -> pack+permlane -> PV. Masked cf blocks skipped entirely (no -inf fill).
// ~130 live VGPRs -> no spill (r13's S[4] = +64 regs caused scratch).
__global__ __launch_bounds__(256, 2) void attn_kernel(
    const unsigned short* __restrict__ Qg, const unsigned short* __restrict__ Kg,
    const unsigned short* __restrict__ Vtg, unsigned short* __restrict__ Yg) {
  __shared__ __align__(16) unsigned char lds[32 * 1024];
  unsigned char* KsB = lds;             // 16KB [128 s][64 d], chunk^(row&7)
  unsigned char* VtB = lds + 16384;     // 16KB [64 d][128 t], chunk^(d&15)

  const int tid = threadIdx.x;
  const int lane = tid & 63, w = tid >> 6;       // w in 0..3
  const int l31 = lane & 31, hi = lane >> 5;
  const int kk = blockIdx.x >> 5;
  const int qc = (kk & 1) ? (kk >> 1) : (15 - (kk >> 1));  // balanced LPT
  const int bh = blockIdx.x & 31;

  const unsigned short* Qbase = Qg + (size_t)bh * T_SEQ * HS;
  const unsigned short* Kbase = Kg + (size_t)bh * T_SEQ * HS;
  const unsigned short* Vtbase = Vtg + (size_t)bh * T_SEQ * HS;  // [64][2048]

  // K staging: thread -> rows (tid>>3)+32k, chunk tid&7 (r13-proven)
  const int ks_row = tid >> 3, ks_cb = tid & 7;
  const int kLds0 = ks_row * 128 + ((ks_cb ^ (ks_row & 7)) << 4);
  const unsigned short* Kg0 = Kbase + ks_row * HS + ks_cb * 8;
  // V staging: thread -> d rows (tid>>4)+16k, chunk tid&15 (kv-chunk = t/8)
  const int vs_d = tid >> 4, vs_m = tid & 15;
  const int vLds0 = vs_d * 256 + ((vs_m ^ (vs_d & 15)) << 4);
  const unsigned short* Vg0 = Vtbase + (size_t)vs_d * T_SEQ + vs_m * 8;

  // Q B-frags: col q = w*32+l31; k-slot (hi,j) -> d = ks*16 + hi*8 + j
  v8s qB[4];
  {
    const unsigned short* qrow = Qbase + (size_t)(qc * 128 + w * 32 + l31) * HS;
#pragma unroll
    for (int ks = 0; ks < 4; ++ks)
      qB[ks] = *(const v8s*)(qrow + ks * 16 + hi * 8);
  }

  v16f zero16 = {};
  v16f O0 = zero16, O1 = zero16;
  float mrun = -1e30f, lrun = 0.f;

  // prologue: tile 0 into regs
  int4 kA[4], vv[4];
#pragma unroll
  for (int k = 0; k < 4; ++k) {
    kA[k] = *(const int4*)(Kg0 + k * 2048);
    vv[k] = *(const int4*)(Vg0 + k * 16 * T_SEQ);
  }

  for (int t = 0; t <= qc; ++t) {
    __syncthreads();  // all reads of previous tile done
#pragma unroll
    for (int k = 0; k < 4; ++k) {
      *(int4*)(KsB + kLds0 + k * 4096) = kA[k];
      *(int4*)(VtB + vLds0 + k * 4096) = vv[k];
    }
    __syncthreads();
    if (t < qc) {  // prefetch next tile (T14: hidden under compute)
      const unsigned short* kp = Kg0 + (t + 1) * 8192;
      const unsigned short* vp = Vg0 + (t + 1) * 128;
#pragma unroll
      for (int k = 0; k < 4; ++k) {
        kA[k] = *(const int4*)(kp + k * 2048);
        vv[k] = *(const int4*)(vp + k * 16 * T_SEQ);
      }
    }

    const bool diag = (t == qc);
    const int cflim = diag ? w : 3;           // wave-uniform

#pragma unroll
    for (int cf = 0; cf < 4; ++cf) {
      if (cf <= cflim) {
        // S^T block cf: lane owns q = w*32+l31; kv rows per reg:
        // kvin = (reg&3) + 8*(reg>>2) + 4*hi  [m74/m101, r13-verified]
        v16f S = zero16;
        __builtin_amdgcn_s_setprio(1);
#pragma unroll
        for (int ks = 0; ks < 4; ++ks) {
          int row = cf * 32 + l31;
          v8s ka = *(const v8s*)(KsB + row * 128 +
                                 ((((ks << 1) + hi) ^ (row & 7)) << 4));
          S = __builtin_amdgcn_mfma_f32_32x32x16_bf16(ka, qB[ks], S, 0, 0, 0);
        }
        __builtin_amdgcn_s_setprio(0);

        if (diag && cf == w) {  // straddle block: mask kv_in > q_in
#pragma unroll
          for (int reg = 0; reg < 16; ++reg) {
            int kvin = (reg & 3) + 8 * (reg >> 2) + 4 * hi;
            if (kvin > l31) S[reg] = -1e30f;
          }
        }

        // per-cf online softmax (exp2 domain; pair lane l^32 shares q)
        float mx = -1e30f;
#pragma unroll
        for (int reg = 0; reg < 16; ++reg) mx = fmaxf(mx, S[reg]);
        mx = fmaxf(mx, __shfl_xor(mx, 32));

        if (!__all(mx - mrun <= 8.0f)) {     // defer-max (T13, THR=8)
          float mn = fmaxf(mrun, mx);
          float alpha = exp2_fast(mrun - mn);
          mrun = mn;
          lrun *= alpha;
#pragma unroll
          for (int reg = 0; reg < 16; ++reg) { O0[reg] *= alpha; O1[reg] *= alpha; }
        }

        float sum = 0.f;
#pragma unroll
        for (int reg = 0; reg < 16; ++reg) {
          float p = exp2_fast(S[reg] - mrun);
          S[reg] = p;
          sum += p;
        }
        sum += __shfl_xor(sum, 32);
        lrun += sum;

        // PV for this cf: 2 ksteps of kv=16; B-frag via cvt_pk + permlane
        __builtin_amdgcn_s_setprio(1);
#pragma unroll
        for (int half = 0; half < 2; ++half) {
          int rb = half * 8;
          unsigned x0 = cvt_pk_bf16(S[rb + 0], S[rb + 1]);
          unsigned x1 = cvt_pk_bf16(S[rb + 2], S[rb + 3]);
          unsigned y0 = cvt_pk_bf16(S[rb + 4], S[rb + 5]);
          unsigned y1 = cvt_pk_bf16(S[rb + 6], S[rb + 7]);
          asm("v_permlane32_swap_b32 %0, %1" : "+v"(x0), "+v"(y0));
          asm("v_permlane32_swap_b32 %0, %1" : "+v"(x1), "+v"(y1));
          union { unsigned u[4]; v8s s; } pb;
          pb.u[0] = x0; pb.u[1] = x1; pb.u[2] = y0; pb.u[3] = y1;
          int ksb = cf * 2 + half;
          {
            int row = l31;   // db = 0
            v8s va = *(const v8s*)(VtB + row * 256 +
                                   ((((ksb << 1) + hi) ^ (row & 15)) << 4));
            O0 = __builtin_amdgcn_mfma_f32_32x32x16_bf16(va, pb.s, O0, 0, 0, 0);
          }
          {
            int row = 32 + l31;  // db = 1
            v8s va = *(const v8s*)(VtB + row * 256 +
                                   ((((ksb << 1) + hi) ^ (row & 15)) << 4));
            O1 = __builtin_amdgcn_mfma_f32_32x32x16_bf16(va, pb.s, O1, 0, 0, 0);
          }
        }
        __builtin_amdgcn_s_setprio(0);
      }
    }
  }

  // epilogue: lane owns q-row tq; d = db*32 + 8*rq + 4*hi + (0..3)
  float invl = 1.0f / lrun;
  int tq = qc * 128 + w * 32 + l31;
  int b = bh >> 4, h = bh & 15;
  size_t ybase = ((size_t)b * T_SEQ + tq) * (NH * HS) + h * 64;
#pragma unroll
  for (int rq = 0; rq < 4; ++rq) {
    int d0 = rq * 8 + hi * 4;
    ushort4 o4;
    o4.x = f2bf(O0[rq * 4 + 0] * invl);
    o4.y = f2bf(O0[rq * 4 + 1] * invl);
    o4.z = f2bf(O0[rq * 4 + 2] * invl);
    o4.w = f2bf(O0[rq * 4 + 3] * invl);
    *(ushort4*)(Yg + ybase + d0) = o4;
    ushort4 o5;
    o5.x = f2bf(O1[rq * 4 + 0] * invl);
    o5.y = f2bf(O1[rq * 4 + 1] * invl);
    o5.z = f2bf(O1[rq * 4 + 2] * invl);
    o5.w = f2bf(O1[rq * 4 + 3] * invl);
    *(ushort4*)(Yg + ybase + 32 + d0) = o5;
  }
}

extern "C" void kernel_launch(void* const* d_in, const int* in_sizes, int n_in,
                              void* d_out, int out_size, void* d_ws, size_t ws_size,
                              hipStream_t stream) {
  (void)in_sizes; (void)n_in; (void)out_size; (void)ws_size;
  const float* x  = (const float*)d_in[0];
  const float* Wq = (const float*)d_in[1];
  const float* Wk = (const float*)d_in[2];
  const float* Wv = (const float*)d_in[3];
  const float* Wo = (const float*)d_in[4];
  const float* bo = (const float*)d_in[5];

  unsigned char* ws = (unsigned char*)d_ws;
  unsigned short* xb  = (unsigned short*)(ws);                      // 8MB
  unsigned short* Wt  = (unsigned short*)(ws + (8u << 20));         // 6MB
  unsigned short* Wot = (unsigned short*)(ws + (14u << 20));        // 2MB
  unsigned short* qkv = (unsigned short*)(ws + (16u << 20));        // 24MB
  unsigned short* Y   = (unsigned short*)(ws + (40u << 20));        // 8MB

  // 1. fused prep: x->bf16 + all weight transposes (one launch)
  prep_kernel<<<dim3(6144), 256, 0, stream>>>(x, Wq, Wk, Wv, Wo, xb, Wt, Wot);

  // 2. fused QKV projection: [4096][1024] x [3072][1024]^T (768 blocks)
  gemm_qkv<<<dim3(768), 256, 0, stream>>>(xb, Wt, qkv, 24);

  // 3. causal flash attention (V pre-transposed per head: [b][h][64][2048])
  const unsigned short* Qp = qkv;
  const unsigned short* Kp = qkv + (size_t)B_SZ * NH * T_SEQ * HS;
  const unsigned short* Vtp = qkv + (size_t)2 * B_SZ * NH * T_SEQ * HS;
  attn_kernel<<<dim3(512), 256, 0, stream>>>(Qp, Kp, Vtp, Y);

  // 4. output projection + bias -> f32 d_out (512 blocks, BM=64)
  gemm_proj<<<dim3(512), 256, 0, stream>>>(Y, Wot, (float*)d_out, bo, 8);
}

// Round 16
// 99.615 us; speedup vs baseline: 1.5716x; 1.5716x over previous
//
#include <hip/hip_runtime.h>

// MHA forward, full-bf16 MFMA pipeline.  (r9 proven config; attn upgraded to
// single-barrier double-buffered K/V staging — indexing unchanged, +buf off)
// ws layout (bytes): xb[8MB] | Wt[6MB: [3][1024][1024] bf16 N-major] | Wot[2MB]
//                    | qkv[24MB: Q,K:[B][H][T][64], V:[B][H][64][T]] | Y[8MB]

typedef short v8s __attribute__((ext_vector_type(8)));
typedef float v4f __attribute__((ext_vector_type(4)));

#define DEVI __device__ __forceinline__

#define B_SZ 2
#define T_SEQ 2048
#define NH 16
#define HS 64
#define CEMB 1024
#define MROWS (B_SZ * T_SEQ)   // 4096
#define KSZ 1024
// Q scale: 1/sqrt(64) * log2(e)  (attention softmax runs in exp2 domain)
#define SCALE_Q 0.18033688011112042f

DEVI unsigned short f2bf(float f) {
  union { float f; unsigned u; } c; c.f = f;
  unsigned u = c.u;
  unsigned r = (u + 0x7FFFu + ((u >> 16) & 1u)) >> 16;   // RNE
  return (unsigned short)r;
}

DEVI float exp2_fast(float x) {         // v_exp_f32 = 2^x
  float r;
  asm("v_exp_f32 %0, %1" : "=v"(r) : "v"(x));
  return r;
}

DEVI unsigned cvt_pk_bf16(float lo, float hi) {  // packs 2 f32 -> 2 bf16 (RNE)
  unsigned r;
  asm("v_cvt_pk_bf16_f32 %0, %1, %2" : "=v"(r) : "v"(lo), "v"(hi));
  return r;
}

// async global -> LDS, 16B per lane (wave-uniform LDS base + lane*16)
DEVI void gload_lds16(const void* g, void* l) {
  __builtin_amdgcn_global_load_lds(
      (const __attribute__((address_space(1))) void*)g,
      (__attribute__((address_space(3))) void*)l, 16, 0, 0);
}

// bijective XCD-contiguous block swizzle (requires nwg % 8 == 0)
DEVI int xcd_swz(int bid, int nwg) {
  int q = nwg >> 3;
  return (bid & 7) * q + (bid >> 3);
}

// ---------------- fused prep: x->bf16 + weight transposes (1 launch) -------
__global__ __launch_bounds__(256, 4) void prep_kernel(
    const float* __restrict__ x, const float* __restrict__ Wq,
    const float* __restrict__ Wk, const float* __restrict__ Wv,
    const float* __restrict__ Wo, unsigned short* __restrict__ xb,
    unsigned short* __restrict__ Wt, unsigned short* __restrict__ Wot) {
  int bid = blockIdx.x;
  if (bid < 2048) {
    int i = bid * 2048 + threadIdx.x * 8;
    float4 a = *(const float4*)(x + i);
    float4 b = *(const float4*)(x + i + 4);
    ushort4 o0, o1;
    o0.x = f2bf(a.x); o0.y = f2bf(a.y); o0.z = f2bf(a.z); o0.w = f2bf(a.w);
    o1.x = f2bf(b.x); o1.y = f2bf(b.y); o1.z = f2bf(b.z); o1.w = f2bf(b.w);
    *(ushort4*)(xb + i) = o0;
    *(ushort4*)(xb + i + 4) = o1;
    return;
  }
  __shared__ float tile[32][33];
  const float* in; unsigned short* out;
  int C, bx, by;
  if (bid < 5120) {
    int b2 = bid - 2048;
    int widx = b2 >> 10, rem = b2 & 1023;
    in = (widx == 0 ? Wq : (widx == 1 ? Wk : Wv));
    int z = rem >> 6;                     // head 0..15
    bx = rem & 1; by = (rem >> 1) & 31;
    C = 64;
    in += (size_t)z * 1024 * 64;
    out = Wt + ((size_t)widx << 20) + (size_t)z * 1024 * 64;
  } else {
    int rem = bid - 5120;
    C = 1024;
    bx = rem & 31; by = rem >> 5;
    in = Wo; out = Wot;
  }
  int c0 = bx * 32, r0 = by * 32;
  int tx = threadIdx.x & 31, ty = threadIdx.x >> 5;
#pragma unroll
  for (int j = 0; j < 4; ++j)
    tile[ty + j * 8][tx] = in[(size_t)(r0 + ty + j * 8) * C + c0 + tx];
  __syncthreads();
#pragma unroll
  for (int j = 0; j < 4; ++j)
    out[(size_t)(c0 + ty + j * 8) * 1024 + r0 + tx] = f2bf(tile[tx][ty + j * 8]);
}

// ------------- GEMM: C = A[M][1024] x Bt[N][1024]^T, bf16 in, f32 acc -------
// 128x128 tile, BK=32, 4 waves; 3-deep counted-vmcnt pipeline with tail peel
// (vmcnt 8/4/0). 1D grid + XCD swizzle. LDS linear for global_load_lds;
// source chunk pre-swizzled (c ^= row&3) + same XOR on fragment reads.
// MODE 0: QKV epilogue; [16,24) N-panels = V via LDS-transpose epilogue.
// MODE 1: out-proj epilogue -> f32 [M][1024] + bias.
template <int MODE>
__global__ __launch_bounds__(256, 3) void gemm_bt(
    const unsigned short* __restrict__ A, const unsigned short* __restrict__ Bt,
    void* __restrict__ Cout, const float* __restrict__ bias, int nbx) {
  __shared__ __align__(16) unsigned char lds[49152];     // As[3]|Bs[3] / Vt_l
  unsigned short* As = (unsigned short*)lds;             // [3][4096]
  unsigned short* Bs = (unsigned short*)(lds + 24576);   // [3][4096]

  const int tid = threadIdx.x;
  const int lane = tid & 63, w = tid >> 6;
  const int wm = w >> 1, wn = w & 1;
  const int lr = lane & 15, lg = lane >> 4;

  const int wg = xcd_swz(blockIdx.x, gridDim.x);
  const int mb = (wg / nbx) * 128, nb = (wg % nbx) * 128;

  v4f acc[4][4];
  v4f zero = {0.f, 0.f, 0.f, 0.f};
#pragma unroll
  for (int i = 0; i < 4; ++i)
#pragma unroll
    for (int j = 0; j < 4; ++j) acc[i][j] = zero;

  const int srow = lane >> 2;
  const int sgcol = ((lane & 3) ^ (srow & 3)) * 8;
  const unsigned short* gA = A + (size_t)(mb + w * 32 + srow) * KSZ + sgcol;
  const unsigned short* gB = Bt + (size_t)(nb + w * 32 + srow) * KSZ + sgcol;
  unsigned short* lA = As + w * 1024;   // wave-uniform; +4096/buf
  unsigned short* lB = Bs + w * 1024;

#define STAGE_G(buf, kb)                                        \
  do {                                                          \
    gload_lds16(gA + (kb), lA + (buf) * 4096);                  \
    gload_lds16(gA + (kb) + 16 * KSZ, lA + (buf) * 4096 + 512); \
    gload_lds16(gB + (kb), lB + (buf) * 4096);                  \
    gload_lds16(gB + (kb) + 16 * KSZ, lB + (buf) * 4096 + 512); \
  } while (0)

  STAGE_G(0, 0);
  STAGE_G(1, 32);
  STAGE_G(2, 64);

  const int NT = KSZ / 32;   // 32 K-steps
  for (int t = 0; t < NT; ++t) {
    if (t < NT - 2)
      asm volatile("s_waitcnt vmcnt(8)" ::: "memory");
    else if (t == NT - 2)
      asm volatile("s_waitcnt vmcnt(4)" ::: "memory");
    else
      asm volatile("s_waitcnt vmcnt(0)" ::: "memory");
    __builtin_amdgcn_s_barrier();

    const int buf = t % 3;
    v8s af[4], bfr[4];
#pragma unroll
    for (int i = 0; i < 4; ++i) {
      int ra = wm * 64 + i * 16 + lr, rb = wn * 64 + i * 16 + lr;
      af[i]  = *(const v8s*)&As[buf * 4096 + ra * 32 + ((lg ^ (lr & 3)) << 3)];
      bfr[i] = *(const v8s*)&Bs[buf * 4096 + rb * 32 + ((lg ^ (lr & 3)) << 3)];
    }
#pragma unroll
    for (int i = 0; i < 4; ++i)
#pragma unroll
      for (int j = 0; j < 4; ++j)
        acc[i][j] = __builtin_amdgcn_mfma_f32_16x16x32_bf16(af[i], bfr[j], acc[i][j], 0, 0, 0);

    asm volatile("s_waitcnt lgkmcnt(0)" ::: "memory");
    __builtin_amdgcn_s_barrier();
    if (t + 3 < NT) STAGE_G(buf, (t + 3) * 32);
  }
#undef STAGE_G

  if (MODE == 0 && (wg % nbx) >= 16) {
    // ---- V-block epilogue: LDS transpose then t-contiguous 16B stores ----
    unsigned short* out = (unsigned short*)Cout;
#pragma unroll
    for (int i = 0; i < 4; ++i) {
      int tl0 = wm * 64 + i * 16 + lg * 4;
      int tc = tl0 >> 3, off = (tl0 & 7) * 2;
#pragma unroll
      for (int j = 0; j < 4; ++j) {
        int dl = wn * 64 + j * 16 + lr;
        unsigned lo = cvt_pk_bf16(acc[i][j][0], acc[i][j][1]);
        unsigned hi = cvt_pk_bf16(acc[i][j][2], acc[i][j][3]);
        unsigned char* p = lds + dl * 256 + ((tc ^ (dl & 15)) << 4) + off;
        *(unsigned*)p = lo;
        *(unsigned*)(p + 4) = hi;
      }
    }
    __syncthreads();
    int b = mb >> 11, mt = mb & 2047;
    int nrem0 = nb & 1023;
    unsigned short* Vg = out + (size_t)(2 * B_SZ * NH) * T_SEQ * HS;
#pragma unroll
    for (int it = 0; it < 8; ++it) {
      int dl = it * 16 + (tid >> 4);
      int tc = tid & 15;
      const unsigned char* p = lds + dl * 256 + ((tc ^ (dl & 15)) << 4);
      int4 vv = *(const int4*)p;
      int nrem = nrem0 + dl;
      int h = nrem >> 6, dd = nrem & 63;
      *(int4*)(Vg + ((size_t)(b * NH + h) * HS + dd) * T_SEQ + mt + tc * 8) = vv;
    }
    return;
  }

#pragma unroll
  for (int i = 0; i < 4; ++i) {
    int mrow0 = mb + wm * 64 + i * 16 + lg * 4;
#pragma unroll
    for (int j = 0; j < 4; ++j) {
      int ncol = nb + wn * 64 + j * 16 + lr;
      if (MODE == 0) {
        int p = ncol >> 10, rem = ncol & 1023, h = rem >> 6, d = rem & 63;
        float sc = (p == 0) ? SCALE_Q : 1.0f;
        unsigned short* out = (unsigned short*)Cout;
#pragma unroll
        for (int r = 0; r < 4; ++r) {
          int mrow = mrow0 + r;
          int b = mrow >> 11, t = mrow & 2047;
          out[((size_t)((p * B_SZ + b) * NH + h) * T_SEQ + t) * HS + d] =
              f2bf(acc[i][j][r] * sc);
        }
      } else {
        float* out = (float*)Cout;
        float bv = bias[ncol];
#pragma unroll
        for (int r = 0; r < 4; ++r)
          out[(size_t)(mrow0 + r) * CEMB + ncol] = acc[i][j][r] + bv;
      }
    }
  }
}

// ------------- causal flash attention, swapped-operand, reg-P, DBUF -------
// 512 threads = 8 waves; wave w owns q rows qc*128 + w*16 .. +15.
// Single-barrier double-buffered K/V staging: per iter
// {barrier; ds_write buf[(t+1)&1] (tile t+1 regs); issue loads tile t+2;
//  compute buf[t&1]} — writes(t)->reads(t+1) and reads(t)->writes(t+1) each
// separated by one __syncthreads (lgkm/vm drained by compiler). All LDS
// indexing identical to the proven r9 kernel + (t&1)*16KB buffer offset.
__global__ __launch_bounds__(512, 2) void attn_kernel(
    const unsigned short* __restrict__ Qg, const unsigned short* __restrict__ Kg,
    const unsigned short* __restrict__ Vtg, unsigned short* __restrict__ Yg) {
  __shared__ __align__(16) unsigned char lds[64 * 1024];
  // [Ks0 | Ks1 | Vt0 | Vt1], 16KB each

  const int tid = threadIdx.x;
  const int lane = tid & 63, w = tid >> 6;
  const int lr = lane & 15, lg = lane >> 4;
  const int qc = 15 - (blockIdx.x >> 5);   // plain LPT (r9 best)
  const int bh = blockIdx.x & 31;

  const unsigned short* Qbase = Qg + (size_t)bh * T_SEQ * HS;
  const unsigned short* Kbase = Kg + (size_t)bh * T_SEQ * HS;
  const unsigned short* Vtbase = Vtg + (size_t)bh * T_SEQ * HS;  // [64][2048]

  const int ks_row = tid >> 3, ks_cb = tid & 7;
  const int kLds0 = ks_row * 128 + ((ks_cb ^ (ks_row & 7)) << 4);
  const unsigned short* Kg0 = Kbase + ks_row * HS + ks_cb * 8;
  const int vs_d = tid >> 4, vs_m = tid & 15;
  const int vLds0 = vs_d * 256 + ((vs_m ^ (vs_d & 15)) << 4);
  const int vbt = ((vs_m >> 2) << 4) + ((vs_m & 3) << 2);
  const unsigned short* Vg0 = Vtbase + (size_t)vs_d * T_SEQ + vbt;

  v8s qA[2];
  {
    const unsigned short* qrow = Qbase + (size_t)(qc * 128 + w * 16 + lr) * HS;
    qA[0] = *(const v8s*)(qrow + lg * 8);
    qA[1] = *(const v8s*)(qrow + 32 + lg * 8);
  }

  v4f O[4];
  v4f zero = {0.f, 0.f, 0.f, 0.f};
#pragma unroll
  for (int d = 0; d < 4; ++d) O[d] = zero;
  float mrun = -1e30f, lrun = 0.f;

  // staging-reg set (tile being carried toward its ds_write)
  int4 gK0, gK1;
  int2 vlo0, vhi0, vlo1, vhi1;

#define LOAD_REGS(tt)                                         \
  do {                                                        \
    const unsigned short* kp = Kg0 + (tt) * (128 * HS);       \
    gK0 = *(const int4*)kp;                                   \
    gK1 = *(const int4*)(kp + 4096);                          \
    const unsigned short* vp = Vg0 + (tt) * 128;              \
    vlo0 = *(const int2*)(vp);                                \
    vhi0 = *(const int2*)(vp + 64);                           \
    vlo1 = *(const int2*)(vp + 32 * T_SEQ);                   \
    vhi1 = *(const int2*)(vp + 32 * T_SEQ + 64);              \
  } while (0)

#define WRITE_BUF(bsel)                                               \
  do {                                                                \
    unsigned char* kb_ = lds + (bsel) * 16384;                        \
    unsigned char* vb_ = lds + 32768 + (bsel) * 16384;                \
    *(int4*)(kb_ + kLds0) = gK0;                                      \
    *(int4*)(kb_ + kLds0 + 8192) = gK1;                               \
    int4 v0_; v0_.x = vlo0.x; v0_.y = vlo0.y; v0_.z = vhi0.x; v0_.w = vhi0.y; \
    int4 v1_; v1_.x = vlo1.x; v1_.y = vlo1.y; v1_.z = vhi1.x; v1_.w = vhi1.y; \
    *(int4*)(vb_ + vLds0) = v0_;                                      \
    *(int4*)(vb_ + vLds0 + 8192) = v1_;                               \
  } while (0)

  // prologue: tile 0 -> buf0; preload tile 1 into regs
  LOAD_REGS(0);
  WRITE_BUF(0);
  if (qc >= 1) LOAD_REGS(1);

  for (int t = 0; t <= qc; ++t) {
    __syncthreads();  // prev iter's reads done; this iter's buf writes visible
    if (t < qc) {
      WRITE_BUF((t + 1) & 1);          // tile t+1 (regs) -> other buffer
      if (t + 2 <= qc) LOAD_REGS(t + 2);  // issue next loads (WAR via compiler)
    }
    const unsigned char* KsB = lds + (t & 1) * 16384;
    const unsigned char* VtB = lds + 32768 + (t & 1) * 16384;

    const int cflim = (t == qc) ? w : 7;

    v4f S[8];
    __builtin_amdgcn_s_setprio(1);
#pragma unroll
    for (int cf = 0; cf < 8; ++cf) {
      if (cf <= cflim) {
        S[cf] = zero;
#pragma unroll
        for (int ks = 0; ks < 2; ++ks) {
          int srow = cf * 16 + lr;
          v8s kb = *(const v8s*)(KsB + srow * 128 +
                                 ((((ks << 2) + lg) ^ (lr & 7)) << 4));
          S[cf] = __builtin_amdgcn_mfma_f32_16x16x32_bf16(kb, qA[ks], S[cf], 0, 0, 0);
        }
      } else {
        S[cf] = (v4f){-1e30f, -1e30f, -1e30f, -1e30f};
      }
    }
    __builtin_amdgcn_s_setprio(0);

    if (t == qc) {
#pragma unroll
      for (int cf = 0; cf < 8; ++cf)
        if (cf == w) {
#pragma unroll
          for (int r = 0; r < 4; ++r)
            if (lg * 4 + r > lr) S[cf][r] = -1e30f;
        }
    }

    float mx = -1e30f;
#pragma unroll
    for (int cf = 0; cf < 8; ++cf)
#pragma unroll
      for (int r = 0; r < 4; ++r) mx = fmaxf(mx, S[cf][r]);
    mx = fmaxf(mx, __shfl_xor(mx, 16));
    mx = fmaxf(mx, __shfl_xor(mx, 32));

    if (!__all(mx - mrun <= 8.0f)) {     // defer-max (T13, THR=8)
      float mn = fmaxf(mrun, mx);
      float alpha = exp2_fast(mrun - mn);
      mrun = mn;
      lrun *= alpha;
#pragma unroll
      for (int df = 0; df < 4; ++df)
#pragma unroll
        for (int r = 0; r < 4; ++r) O[df][r] *= alpha;
    }

    float sum = 0.f;
#pragma unroll
    for (int cf = 0; cf < 8; ++cf)
#pragma unroll
      for (int r = 0; r < 4; ++r) {
        float p = exp2_fast(S[cf][r] - mrun);
        S[cf][r] = p;
        sum += p;
      }
    sum += __shfl_xor(sum, 16);
    sum += __shfl_xor(sum, 32);
    lrun += sum;

    unsigned pk0[8], pk1[8];
#pragma unroll
    for (int cf = 0; cf < 8; ++cf) {
      pk0[cf] = cvt_pk_bf16(S[cf][0], S[cf][1]);
      pk1[cf] = cvt_pk_bf16(S[cf][2], S[cf][3]);
    }

    __builtin_amdgcn_s_setprio(1);
#pragma unroll
    for (int c = 0; c < 4; ++c) {
      if (t != qc || c <= w) {
        union { unsigned u[4]; v8s s; } pu;
        pu.u[0] = pk0[c]; pu.u[1] = pk1[c];
        pu.u[2] = pk0[c + 4]; pu.u[3] = pk1[c + 4];
        v8s pa = pu.s;
#pragma unroll
        for (int df = 0; df < 4; ++df) {
          int d = df * 16 + lr;
          v8s va = *(const v8s*)(VtB + d * 256 +
                                 ((((c << 2) + lg) ^ lr) << 4));
          O[df] = __builtin_amdgcn_mfma_f32_16x16x32_bf16(va, pa, O[df], 0, 0, 0);
        }
      }
    }
    __builtin_amdgcn_s_setprio(0);
  }
#undef LOAD_REGS
#undef WRITE_BUF

  float invl = 1.0f / lrun;
  int tq = qc * 128 + w * 16 + lr;
  int b = bh >> 4, h = bh & 15;
  size_t ybase = ((size_t)b * T_SEQ + tq) * (NH * HS) + h * 64;
#pragma unroll
  for (int df = 0; df < 4; ++df) {
    ushort4 o4;
    o4.x = f2bf(O[df][0] * invl);
    o4.y = f2bf(O[df][1] * invl);
    o4.z = f2bf(O[df][2] * invl);
    o4.w = f2bf(O[df][3] * invl);
    *(ushort4*)(Yg + ybase + df * 16 + lg * 4) = o4;
  }
}

extern "C" void kernel_launch(void* const* d_in, const int* in_sizes, int n_in,
                              void* d_out, int out_size, void* d_ws, size_t ws_size,
                              hipStream_t stream) {
  (void)in_sizes; (void)n_in; (void)out_size; (void)ws_size;
  const float* x  = (const float*)d_in[0];
  const float* Wq = (const float*)d_in[1];
  const float* Wk = (const float*)d_in[2];
  const float* Wv = (const float*)d_in[3];
  const float* Wo = (const float*)d_in[4];
  const float* bo = (const float*)d_in[5];

  unsigned char* ws = (unsigned char*)d_ws;
  unsigned short* xb  = (unsigned short*)(ws);                      // 8MB
  unsigned short* Wt  = (unsigned short*)(ws + (8u << 20));         // 6MB
  unsigned short* Wot = (unsigned short*)(ws + (14u << 20));        // 2MB
  unsigned short* qkv = (unsigned short*)(ws + (16u << 20));        // 24MB
  unsigned short* Y   = (unsigned short*)(ws + (40u << 20));        // 8MB

  // 1. fused prep: x->bf16 + all weight transposes (one launch)
  prep_kernel<<<dim3(6144), 256, 0, stream>>>(x, Wq, Wk, Wv, Wo, xb, Wt, Wot);

  // 2. fused QKV projection: [4096][1024] x [3072][1024]^T (768 blocks)
  gemm_bt<0><<<dim3(768), 256, 0, stream>>>(xb, Wt, qkv, nullptr, 24);

  // 3. causal flash attention (V pre-transposed per head: [b][h][64][2048])
  const unsigned short* Qp = qkv;
  const unsigned short* Kp = qkv + (size_t)B_SZ * NH * T_SEQ * HS;
  const unsigned short* Vtp = qkv + (size_t)2 * B_SZ * NH * T_SEQ * HS;
  attn_kernel<<<dim3(512), 512, 0, stream>>>(Qp, Kp, Vtp, Y);

  // 4. output projection + bias -> f32 d_out (256 blocks)
  gemm_bt<1><<<dim3(256), 256, 0, stream>>>(Y, Wot, d_out, bo, 8);
}